// Round 13
// baseline (456.736 us; speedup 1.0000x reference)
//
#include <hip/hip_runtime.h>
#include <float.h>

#define D_DIM 768
#define K_DIM 500
#define NDT   24          // 768 / 32 D-tiles
#define BM    64          // rows per block
#define NTH   256
#define PB_STRIDE 100352  // padded per-half partial stride (rows)

typedef _Float16 f16x8 __attribute__((ext_vector_type(8)));
typedef float    f32x4 __attribute__((ext_vector_type(4)));

// ws layout:
//   0        : cnorm   float[512]                 (2 KB)
//   4096     : partial double[16*512]             (64 KB)
//   131072   : BpH     _Float16[24*512*32]        (768 KB)
//   917504   : BpL     _Float16[24*512*32]        (768 KB)
//   1703936  : pbv     float[2*PB_STRIDE]         (~800 KB)
//   2506752  : pbi     int[2*PB_STRIDE]           (~800 KB)

// ---------------- cnorm prep (exact, fp64) ----------------
__global__ void cnorm_partial_kernel(const float* __restrict__ C,
                                     double* __restrict__ partial, int K) {
    const int k = threadIdx.x;
    const int w = blockIdx.x;    // 0..15
    double s = 0.0;
    if (k < K) {
        const int d0 = w * (D_DIM / 16);
        for (int d = d0; d < d0 + (D_DIM / 16); ++d) {
            const float c = C[(size_t)d * K + k];
            s = fma((double)c, (double)c, s);
        }
    }
    partial[w * 512 + k] = s;
}

__global__ void cnorm_finish_kernel(const double* __restrict__ partial,
                                    float* __restrict__ cnorm, int K) {
    const int k = threadIdx.x;
    if (k < K) {
        double s = 0.0;
        for (int w = 0; w < 16; ++w) s += partial[w * 512 + k];
        cnorm[k] = (float)s;
    } else {
        cnorm[k] = FLT_MAX;
    }
}

// ---------------- pack C into fragment-ready f16 hi/lo planes ----------------
__global__ void packB_kernel(const float* __restrict__ C,
                             _Float16* __restrict__ BpH,
                             _Float16* __restrict__ BpL) {
    const int idx = blockIdx.x * 256 + threadIdx.x;   // 0..12287
    const int col = idx & 511;
    const int dt  = idx >> 9;                         // 0..23
    f16x8 h[4], l[4];
    #pragma unroll
    for (int c = 0; c < 4; ++c)
        #pragma unroll
        for (int j = 0; j < 8; ++j) {
            const int k = c * 8 + j;
            const float v = (col < K_DIM)
                          ? C[(size_t)(dt * 32 + k) * K_DIM + col] : 0.0f;
            const _Float16 hh = (_Float16)v;
            h[c][j] = hh;
            l[c][j] = (_Float16)(v - (float)hh);
        }
    f16x8* dH = (f16x8*)(BpH + ((size_t)dt * 512 + col) * 32);
    f16x8* dL = (f16x8*)(BpL + ((size_t)dt * 512 + col) * 32);
    #pragma unroll
    for (int c = 0; c < 4; ++c) { dH[c] = h[c]; dL[c] = l[c]; }
}

// --- main: barrier-free LDS-free fp16-split MFMA, frag-order A, argmin -------
__launch_bounds__(NTH, 3)
__global__ void assign_kernel(const float* __restrict__ feat,
                              const _Float16* __restrict__ BpH,
                              const _Float16* __restrict__ BpL,
                              const float* __restrict__ cnorm,
                              float* __restrict__ pbv,
                              int* __restrict__ pbi,
                              int T) {
    __shared__ float red_v[BM * 4];   // epilogue scratch only
    __shared__ int   red_i[BM * 4];

    const int tid  = threadIdx.x;
    const int wn   = tid >> 6;    // 0..3 (64-col slice)
    const int lane = tid & 63;
    const int l15  = lane & 15;
    const int kg   = lane >> 4;   // 0..3 (k-group)
    const int bid  = blockIdx.x;
    const int half = bid & 1;     // col half: 0 -> cols 0..255, 1 -> 256..511
    const int R0   = (bid >> 1) * BM;

    // A fragment-order row pointers (clamped; dup rows discarded at write).
    // Lane (kg,l15), tile m: rows m*16+l15, k-chunk kg -> 8 floats.
    // Instruction footprint: 16 consecutive rows x 2 sectors — L1-paired.
    int r0 = R0 +  0 + l15; r0 = r0 < T ? r0 : T - 1;
    int r1 = R0 + 16 + l15; r1 = r1 < T ? r1 : T - 1;
    int r2 = R0 + 32 + l15; r2 = r2 < T ? r2 : T - 1;
    int r3 = R0 + 48 + l15; r3 = r3 < T ? r3 : T - 1;
    const float* ap0 = feat + (size_t)r0 * D_DIM + kg * 8;
    const float* ap1 = feat + (size_t)r1 * D_DIM + kg * 8;
    const float* ap2 = feat + (size_t)r2 * D_DIM + kg * 8;
    const float* ap3 = feat + (size_t)r3 * D_DIM + kg * 8;

    // B fragment base: global col = half*256 + wn*64 + nh*16 + l15, chunk kg
    const int colbase = half * 256 + wn * 64 + l15;
    const _Float16* bpH = BpH + (size_t)colbase * 32 + kg * 8;
    const _Float16* bpL = BpL + (size_t)colbase * 32 + kg * 8;

    f32x4 acc[4][4];
    #pragma unroll
    for (int m = 0; m < 4; ++m)
        #pragma unroll
        for (int n = 0; n < 4; ++n) acc[m][n] = (f32x4){0.f, 0.f, 0.f, 0.f};

#define SPLIT8(V0, V1, H, L) do {                                              \
    const float fa_[8] = {(V0).x, (V0).y, (V0).z, (V0).w,                      \
                          (V1).x, (V1).y, (V1).z, (V1).w};                     \
    _Pragma("unroll")                                                          \
    for (int j = 0; j < 8; ++j) {                                              \
        const _Float16 hh = (_Float16)fa_[j];                                  \
        (H)[j] = hh; (L)[j] = (_Float16)(fa_[j] - (float)hh);                  \
    }                                                                          \
} while (0)

    #pragma unroll 1
    for (int dt = 0; dt < NDT; ++dt) {
        const int o = dt * 32;

        // ---- raw A loads issued FIRST (oldest in vmcnt queue: the splits
        //      below wait only on A while B stays in flight)
        const float4 a00 = *(const float4*)(ap0 + o);
        const float4 a01 = *(const float4*)(ap0 + o + 4);
        const float4 a10 = *(const float4*)(ap1 + o);
        const float4 a11 = *(const float4*)(ap1 + o + 4);
        const float4 a20 = *(const float4*)(ap2 + o);
        const float4 a21 = *(const float4*)(ap2 + o + 4);
        const float4 a30 = *(const float4*)(ap3 + o);
        const float4 a31 = *(const float4*)(ap3 + o + 4);

        // ---- B fragment loads (retire under the A-split VALU below)
        const size_t bo = (size_t)dt * 16384;   // dt*512*32 elements
        f16x8 bH[4], bL[4];
        #pragma unroll
        for (int nh = 0; nh < 4; ++nh) {
            bH[nh] = *(const f16x8*)(bpH + bo + nh * 512);
            bL[nh] = *(const f16x8*)(bpL + bo + nh * 512);
        }

        // ---- in-register fp32 -> f16 hi/lo split (frag-ready, no LDS)
        f16x8 aH[4], aL[4];
        SPLIT8(a00, a01, aH[0], aL[0]);
        SPLIT8(a10, a11, aH[1], aL[1]);
        SPLIT8(a20, a21, aH[2], aL[2]);
        SPLIT8(a30, a31, aH[3], aL[3]);

        // ---- MFMA cluster (48 x 16x16x32)
        __builtin_amdgcn_s_setprio(1);
        #pragma unroll
        for (int nh = 0; nh < 4; ++nh)
            #pragma unroll
            for (int m = 0; m < 4; ++m) {
                f32x4 a = acc[m][nh];
                a = __builtin_amdgcn_mfma_f32_16x16x32_f16(aH[m], bH[nh], a, 0, 0, 0);
                a = __builtin_amdgcn_mfma_f32_16x16x32_f16(aL[m], bH[nh], a, 0, 0, 0);
                a = __builtin_amdgcn_mfma_f32_16x16x32_f16(aH[m], bL[nh], a, 0, 0, 0);
                acc[m][nh] = a;
            }
        __builtin_amdgcn_s_setprio(0);
    }
#undef SPLIT8

    // ---------------- epilogue: partial argmin over this block's 256 cols ----
    float cn[4];
    #pragma unroll
    for (int nh = 0; nh < 4; ++nh)
        cn[nh] = cnorm[half * 256 + wn * 64 + nh * 16 + l15];

    #pragma unroll
    for (int m = 0; m < 4; ++m) {
        #pragma unroll
        for (int r = 0; r < 4; ++r) {
            float best = cn[0] - 2.0f * acc[m][0][r];
            int   bi   = colbase;
            #pragma unroll
            for (int nh = 1; nh < 4; ++nh) {
                const int col = colbase + nh * 16;
                const float s = cn[nh] - 2.0f * acc[m][nh][r];
                if (s < best || (s == best && col < bi)) { best = s; bi = col; }
            }
            #pragma unroll
            for (int msk = 1; msk < 16; msk <<= 1) {
                const float ov = __shfl_xor(best, msk, 64);
                const int   oi = __shfl_xor(bi,   msk, 64);
                if (ov < best || (ov == best && oi < bi)) { best = ov; bi = oi; }
            }
            if (l15 == 0) {
                const int rl = m * 16 + kg * 4 + r;
                red_v[rl * 4 + wn] = best;
                red_i[rl * 4 + wn] = bi;
            }
        }
    }
    __syncthreads();

    if (tid < BM) {
        float bv = red_v[tid * 4];
        int   bi = red_i[tid * 4];
        #pragma unroll
        for (int w = 1; w < 4; ++w) {
            const float v = red_v[tid * 4 + w];
            const int   i = red_i[tid * 4 + w];
            if (v < bv || (v == bv && i < bi)) { bv = v; bi = i; }
        }
        const int r = R0 + tid;
        if (r < T) {
            pbv[(size_t)half * PB_STRIDE + r] = bv;
            pbi[(size_t)half * PB_STRIDE + r] = bi;
        }
    }
}

// ---------------- combine the two col-half partials ----------------
__global__ void combine_kernel(const float* __restrict__ pbv,
                               const int* __restrict__ pbi,
                               int* __restrict__ out, int T) {
    const int r = blockIdx.x * 256 + threadIdx.x;
    if (r < T) {
        const float s0 = pbv[r];
        const int   i0 = pbi[r];
        const float s1 = pbv[PB_STRIDE + r];
        const int   i1 = pbi[PB_STRIDE + r];
        // exact tie -> half 0 (lower index), matching numpy argmin
        out[r] = (s1 < s0) ? i1 : i0;
    }
}

extern "C" void kernel_launch(void* const* d_in, const int* in_sizes, int n_in,
                              void* d_out, int out_size, void* d_ws, size_t ws_size,
                              hipStream_t stream) {
    const float* feat = (const float*)d_in[0];
    const float* C    = (const float*)d_in[1];
    int* out          = (int*)d_out;
    const int T = in_sizes[0] / D_DIM;   // 100000
    const int K = in_sizes[1] / D_DIM;   // 500

    float*     cnorm   = (float*)d_ws;
    double*    partial = (double*)((char*)d_ws + 4096);
    _Float16*  BpH     = (_Float16*)((char*)d_ws + 131072);
    _Float16*  BpL     = (_Float16*)((char*)d_ws + 917504);
    float*     pbv     = (float*)((char*)d_ws + 1703936);
    int*       pbi     = (int*)((char*)d_ws + 2506752);

    hipLaunchKernelGGL(cnorm_partial_kernel, dim3(16), dim3(512), 0, stream,
                       C, partial, K);
    hipLaunchKernelGGL(cnorm_finish_kernel, dim3(1), dim3(512), 0, stream,
                       partial, cnorm, K);
    hipLaunchKernelGGL(packB_kernel, dim3(48), dim3(256), 0, stream,
                       C, BpH, BpL);

    const int nrb = (T + BM - 1) / BM;            // row blocks
    hipLaunchKernelGGL(assign_kernel, dim3(nrb * 2), dim3(NTH), 0, stream,
                       feat, BpH, BpL, cnorm, pbv, pbi, T);
    hipLaunchKernelGGL(combine_kernel, dim3((T + 255) / 256), dim3(256), 0, stream,
                       pbv, pbi, out, T);
}